// Round 1
// baseline (390.944 us; speedup 1.0000x reference)
//
#include <hip/hip_runtime.h>

#define THRESH   0.7f
#define BASEU    0x3F333334u   // bit pattern of smallest float > 0.7f
#define NBINS    2048          // top-level bins, (u-BASEU)>>12 -> 1229 used
#define NSUB     4096          // patterns per top-level bin (2^12)
#define NBLOCKS  2048
#define NTHREADS 256

struct Ws {
  double   sum_lt;      // sum of losses where p <  0.7f
  double   sum_eq;      // sum of losses where p == 0.7f
  double   prefix_sum;  // fallback: loss sum for all p < selected bin
  unsigned cnt_lt;
  unsigned cnt_eq;
  unsigned done;        // 1 => common case, out already written
  unsigned fin1;
  unsigned fin3;
  unsigned fin5;
  unsigned selBin;
  unsigned rank_r;
  unsigned prefix_cnt;
  unsigned pad[7];
  unsigned Hcnt[NBINS];
  float    Hsum[NBINS];
  unsigned subCnt[NSUB];
  float    subSum[NSUB];
};

// t is exactly 0.0 or 1.0, so BCE collapses to a single log.
// Reference clamps each log term at -100 (torch BCELoss semantics).
__device__ __forceinline__ float bce_loss(float p, float t) {
  float x = (t > 0.5f) ? p : (1.0f - p);
  return -fmaxf(__logf(x), -100.0f);
}

// ---------------- K1: fused streaming pass (the hot kernel) ----------------
__global__ __launch_bounds__(NTHREADS) void k_main(
    const float* __restrict__ pred, const float* __restrict__ targ,
    float* __restrict__ out, Ws* __restrict__ ws, int n, int kidx, int nblocks) {
  int tid = blockIdx.x * blockDim.x + threadIdx.x;
  int stride = gridDim.x * blockDim.x;
  int nvec = n >> 2;
  const float4* p4 = (const float4*)pred;
  const float4* t4 = (const float4*)targ;

  float s_lt = 0.f, s_eq = 0.f;
  unsigned c_lt = 0u, c_eq = 0u;

  for (int i = tid; i < nvec; i += stride) {
    float4 p = p4[i];
    float4 t = t4[i];
    float pa[4] = {p.x, p.y, p.z, p.w};
    float ta[4] = {t.x, t.y, t.z, t.w};
#pragma unroll
    for (int c = 0; c < 4; ++c) {
      float pv = pa[c];
      float loss = bce_loss(pv, ta[c]);
      if (pv < THRESH)       { c_lt++; s_lt += loss; }
      else if (pv == THRESH) { c_eq++; s_eq += loss; }
    }
  }
  // scalar tail (n % 4)
  for (int i = (nvec << 2) + tid; i < n; i += stride) {
    float pv = pred[i];
    float loss = bce_loss(pv, targ[i]);
    if (pv < THRESH)       { c_lt++; s_lt += loss; }
    else if (pv == THRESH) { c_eq++; s_eq += loss; }
  }

  // wave(64) reduce
#pragma unroll
  for (int off = 32; off > 0; off >>= 1) {
    s_lt += __shfl_down(s_lt, off);
    s_eq += __shfl_down(s_eq, off);
    c_lt += __shfl_down(c_lt, off);
    c_eq += __shfl_down(c_eq, off);
  }
  __shared__ float    red_slt[4], red_seq[4];
  __shared__ unsigned red_clt[4], red_ceq[4];
  int wave = threadIdx.x >> 6;
  if ((threadIdx.x & 63) == 0) {
    red_slt[wave] = s_lt; red_seq[wave] = s_eq;
    red_clt[wave] = c_lt; red_ceq[wave] = c_eq;
  }
  __syncthreads();
  if (threadIdx.x == 0) {
    float    tslt = red_slt[0] + red_slt[1] + red_slt[2] + red_slt[3];
    float    tseq = red_seq[0] + red_seq[1] + red_seq[2] + red_seq[3];
    unsigned tclt = red_clt[0] + red_clt[1] + red_clt[2] + red_clt[3];
    unsigned tceq = red_ceq[0] + red_ceq[1] + red_ceq[2] + red_ceq[3];
    atomicAdd(&ws->sum_lt, (double)tslt);
    atomicAdd(&ws->sum_eq, (double)tseq);
    atomicAdd(&ws->cnt_lt, tclt);
    atomicAdd(&ws->cnt_eq, tceq);
    __threadfence();
    unsigned prev = atomicAdd(&ws->fin1, 1u);
    if (prev == (unsigned)(nblocks - 1)) {   // last block finalizes
      __threadfence();
      double   slt = atomicAdd(&ws->sum_lt, 0.0);
      unsigned clt = atomicAdd(&ws->cnt_lt, 0u);
      unsigned ceq = atomicAdd(&ws->cnt_eq, 0u);
      unsigned long long cle = (unsigned long long)clt + ceq;
      // p_sorted[k] <= 0.7f  <=>  count(p <= 0.7f) >= k+1  => threshold = 0.7f
      if (cle > (unsigned long long)kidx) {
        out[0] = (float)(slt / (double)clt);
        ws->done = 1u;
      }
      // else done stays 0 (fallback kernels take over)
    }
  }
}

// ------- K3: fallback level-1 histogram over p>0.7 (early-exit normally) ----
__global__ __launch_bounds__(NTHREADS) void k_hist(
    const float* __restrict__ pred, const float* __restrict__ targ,
    Ws* __restrict__ ws, int n, int kidx, int nblocks) {
  if (ws->done) return;
  __shared__ unsigned hc[NBINS];
  __shared__ float    hs[NBINS];
  for (int i = threadIdx.x; i < NBINS; i += NTHREADS) { hc[i] = 0u; hs[i] = 0.f; }
  __syncthreads();

  int tid = blockIdx.x * blockDim.x + threadIdx.x;
  int stride = gridDim.x * blockDim.x;
  int nvec = n >> 2;
  const float4* p4 = (const float4*)pred;
  const float4* t4 = (const float4*)targ;
  for (int i = tid; i < nvec; i += stride) {
    float4 p = p4[i];
    float4 t = t4[i];
    float pa[4] = {p.x, p.y, p.z, p.w};
    float ta[4] = {t.x, t.y, t.z, t.w};
#pragma unroll
    for (int c = 0; c < 4; ++c) {
      float pv = pa[c];
      if (pv > THRESH) {
        unsigned b = (__float_as_uint(pv) - BASEU) >> 12;
        if (b > NBINS - 1) b = NBINS - 1;
        atomicAdd(&hc[b], 1u);
        atomicAdd(&hs[b], bce_loss(pv, ta[c]));
      }
    }
  }
  for (int i = (nvec << 2) + tid; i < n; i += stride) {
    float pv = pred[i];
    if (pv > THRESH) {
      unsigned b = (__float_as_uint(pv) - BASEU) >> 12;
      if (b > NBINS - 1) b = NBINS - 1;
      atomicAdd(&hc[b], 1u);
      atomicAdd(&hs[b], bce_loss(pv, targ[i]));
    }
  }
  __syncthreads();
  for (int i = threadIdx.x; i < NBINS; i += NTHREADS) {
    if (hc[i])        atomicAdd(&ws->Hcnt[i], hc[i]);
    if (hs[i] != 0.f) atomicAdd(&ws->Hsum[i], hs[i]);
  }
  __threadfence();
  if (threadIdx.x == 0) {
    unsigned prev = atomicAdd(&ws->fin3, 1u);
    if (prev == (unsigned)(nblocks - 1)) {
      __threadfence();
      unsigned long long cum  = (unsigned long long)atomicAdd(&ws->cnt_lt, 0u) +
                                 atomicAdd(&ws->cnt_eq, 0u);
      double             csum = ws->sum_lt + ws->sum_eq;
      for (int b = 0; b < NBINS; ++b) {
        unsigned hcnt = atomicAdd(&ws->Hcnt[b], 0u);
        if (cum + hcnt > (unsigned long long)kidx) {
          ws->selBin     = (unsigned)b;
          ws->rank_r     = (unsigned)((unsigned long long)kidx - cum);
          ws->prefix_cnt = (unsigned)cum;
          ws->prefix_sum = csum;
          break;
        }
        cum  += hcnt;
        csum += (double)atomicAdd(&ws->Hsum[b], 0.f);
      }
    }
  }
}

// ------- K5: fallback level-2 (exact bit pattern) + final (early-exit) ------
__global__ __launch_bounds__(NTHREADS) void k_sub(
    const float* __restrict__ pred, const float* __restrict__ targ,
    float* __restrict__ out, Ws* __restrict__ ws, int n, int nblocks) {
  if (ws->done) return;
  unsigned base = BASEU + (ws->selBin << 12);
  __shared__ unsigned sc[NSUB];
  __shared__ float    ssm[NSUB];
  for (int i = threadIdx.x; i < NSUB; i += NTHREADS) { sc[i] = 0u; ssm[i] = 0.f; }
  __syncthreads();

  int tid = blockIdx.x * blockDim.x + threadIdx.x;
  int stride = gridDim.x * blockDim.x;
  int nvec = n >> 2;
  const float4* p4 = (const float4*)pred;
  const float4* t4 = (const float4*)targ;
  for (int i = tid; i < nvec; i += stride) {
    float4 p = p4[i];
    float4 t = t4[i];
    float pa[4] = {p.x, p.y, p.z, p.w};
    float ta[4] = {t.x, t.y, t.z, t.w};
#pragma unroll
    for (int c = 0; c < 4; ++c) {
      unsigned u = __float_as_uint(pa[c]);
      if (u >= base && u < base + NSUB) {
        atomicAdd(&sc[u - base], 1u);
        atomicAdd(&ssm[u - base], bce_loss(pa[c], ta[c]));
      }
    }
  }
  for (int i = (nvec << 2) + tid; i < n; i += stride) {
    unsigned u = __float_as_uint(pred[i]);
    if (u >= base && u < base + NSUB) {
      atomicAdd(&sc[u - base], 1u);
      atomicAdd(&ssm[u - base], bce_loss(pred[i], targ[i]));
    }
  }
  __syncthreads();
  for (int i = threadIdx.x; i < NSUB; i += NTHREADS) {
    if (sc[i])         atomicAdd(&ws->subCnt[i], sc[i]);
    if (ssm[i] != 0.f) atomicAdd(&ws->subSum[i], ssm[i]);
  }
  __threadfence();
  if (threadIdx.x == 0) {
    unsigned prev = atomicAdd(&ws->fin5, 1u);
    if (prev == (unsigned)(nblocks - 1)) {
      __threadfence();
      unsigned r = ws->rank_r;
      unsigned long long cum = 0;
      double csum = 0.0;
      for (int i = 0; i < NSUB; ++i) {
        unsigned c = atomicAdd(&ws->subCnt[i], 0u);
        if (cum + c > (unsigned long long)r) {
          unsigned long long cnt_final = (unsigned long long)ws->prefix_cnt + cum;
          double sum_final = ws->prefix_sum + csum;
          out[0] = (float)(sum_final / (double)cnt_final);
          break;
        }
        cum  += c;
        csum += (double)atomicAdd(&ws->subSum[i], 0.f);
      }
    }
  }
}

extern "C" void kernel_launch(void* const* d_in, const int* in_sizes, int n_in,
                              void* d_out, int out_size, void* d_ws, size_t ws_size,
                              hipStream_t stream) {
  const float* pred = (const float*)d_in[0];
  const float* targ = (const float*)d_in[1];
  float* out = (float*)d_out;
  Ws* ws = (Ws*)d_ws;
  int n = in_sizes[0];
  // min_kept = min(int(0.5*(n-1)), n-1); exact for positive n (trunc == floor)
  long long kll = (long long)(n - 1) / 2;
  if (kll > (long long)(n - 1)) kll = n - 1;
  int kidx = (int)kll;

  hipMemsetAsync(d_ws, 0, sizeof(Ws), stream);
  k_main<<<NBLOCKS, NTHREADS, 0, stream>>>(pred, targ, out, ws, n, kidx, NBLOCKS);
  k_hist<<<NBLOCKS, NTHREADS, 0, stream>>>(pred, targ, ws, n, kidx, NBLOCKS);
  k_sub <<<NBLOCKS, NTHREADS, 0, stream>>>(pred, targ, out, ws, n, NBLOCKS);
}